// Round 1
// baseline (14.101 us; speedup 1.0000x reference)
//
#include <hip/hip_runtime.h>
#include <math.h>

#define H1 1024
#define H2 512

__device__ __forceinline__ float sigmoidf_(float x) {
    return 1.0f / (1.0f + __expf(-x));
}

// Kernel 1:
//   blocks [0, 1024): compute h1[j] (full layer-1 GRU cell for one element)
//   blocks [1024, 1024+1536): compute gh2[row] = dot(h2_in, w_hh2[row]) + b_hh2[row]
__global__ __launch_bounds__(256) void gru_k1(
    const int* __restrict__ ids,
    const float* __restrict__ h1_in,
    const float* __restrict__ h2_in,
    const float* __restrict__ emb,
    const float* __restrict__ w_ih1,
    const float* __restrict__ w_hh1,
    const float* __restrict__ b_ih1,
    const float* __restrict__ b_hh1,
    const float* __restrict__ w_hh2,
    const float* __restrict__ b_hh2,
    float* __restrict__ d_out,
    float* __restrict__ gh2_ws)
{
    __shared__ float red[6][4];
    const int t = threadIdx.x;
    const int wave = t >> 6, lane = t & 63;
    const int b = blockIdx.x;

    if (b < H1) {
        const int j = b;
        const float* x = emb + (size_t)ids[0] * H1;
        const float4 x4 = ((const float4*)x)[t];      // 4 elems/thread, 1024 total
        const float4 h4 = ((const float4*)h1_in)[t];

        float acc[6];
#pragma unroll
        for (int g = 0; g < 3; ++g) {
            const float4 a = ((const float4*)(w_ih1 + (size_t)(g * H1 + j) * H1))[t];
            const float4 c = ((const float4*)(w_hh1 + (size_t)(g * H1 + j) * H1))[t];
            acc[g]     = x4.x * a.x + x4.y * a.y + x4.z * a.z + x4.w * a.w;
            acc[3 + g] = h4.x * c.x + h4.y * c.y + h4.z * c.z + h4.w * c.w;
        }
#pragma unroll
        for (int g = 0; g < 6; ++g) {
            float v = acc[g];
#pragma unroll
            for (int o = 32; o; o >>= 1) v += __shfl_down(v, o, 64);
            if (lane == 0) red[g][wave] = v;
        }
        __syncthreads();
        if (t == 0) {
            float s[6];
#pragma unroll
            for (int g = 0; g < 6; ++g)
                s[g] = red[g][0] + red[g][1] + red[g][2] + red[g][3];
            const float xr = s[0] + b_ih1[j];
            const float xz = s[1] + b_ih1[j + H1];
            const float xn = s[2] + b_ih1[j + 2 * H1];
            const float hr = s[3] + b_hh1[j];
            const float hz = s[4] + b_hh1[j + H1];
            const float hn = s[5] + b_hh1[j + 2 * H1];
            const float r = sigmoidf_(xr + hr);
            const float z = sigmoidf_(xz + hz);
            const float n = tanhf(xn + r * hn);
            const float h = (1.0f - z) * n + z * h1_in[j];
            d_out[H2 + j] = h;   // h1 lives at flat offset 512
        }
    } else {
        const int row = b - H1;  // [0, 1536)
        const float2 hv = ((const float2*)h2_in)[t];   // 2 elems/thread, 512 total
        const float2 wv = ((const float2*)(w_hh2 + (size_t)row * H2))[t];
        float v = hv.x * wv.x + hv.y * wv.y;
#pragma unroll
        for (int o = 32; o; o >>= 1) v += __shfl_down(v, o, 64);
        if (lane == 0) red[0][wave] = v;
        __syncthreads();
        if (t == 0)
            gh2_ws[row] = red[0][0] + red[0][1] + red[0][2] + red[0][3] + b_hh2[row];
    }
}

// Kernel 2: 512 blocks; block j computes gx2 rows {j, j+512, j+1024} against h1
// (read back from d_out) and finishes the layer-2 GRU cell.
__global__ __launch_bounds__(256) void gru_k2(
    const float* __restrict__ h2_in,
    const float* __restrict__ w_ih2,
    const float* __restrict__ b_ih2,
    const float* __restrict__ gh2_ws,
    float* __restrict__ d_out)
{
    __shared__ float red[3][4];
    const int t = threadIdx.x;
    const int wave = t >> 6, lane = t & 63;
    const int j = blockIdx.x;  // [0, 512)

    const float* h1 = d_out + H2;          // written by gru_k1
    const float4 h4 = ((const float4*)h1)[t];

    float acc[3];
#pragma unroll
    for (int g = 0; g < 3; ++g) {
        const float4 a = ((const float4*)(w_ih2 + (size_t)(g * H2 + j) * H1))[t];
        acc[g] = h4.x * a.x + h4.y * a.y + h4.z * a.z + h4.w * a.w;
    }
#pragma unroll
    for (int g = 0; g < 3; ++g) {
        float v = acc[g];
#pragma unroll
        for (int o = 32; o; o >>= 1) v += __shfl_down(v, o, 64);
        if (lane == 0) red[g][wave] = v;
    }
    __syncthreads();
    if (t == 0) {
        const float xr = red[0][0] + red[0][1] + red[0][2] + red[0][3] + b_ih2[j];
        const float xz = red[1][0] + red[1][1] + red[1][2] + red[1][3] + b_ih2[j + H2];
        const float xn = red[2][0] + red[2][1] + red[2][2] + red[2][3] + b_ih2[j + 2 * H2];
        const float hr = gh2_ws[j];
        const float hz = gh2_ws[j + H2];
        const float hn = gh2_ws[j + 2 * H2];
        const float r = sigmoidf_(xr + hr);
        const float z = sigmoidf_(xz + hz);
        const float n = tanhf(xn + r * hn);
        const float h = (1.0f - z) * n + z * h2_in[j];
        d_out[j] = h;            // output (== h2)
        d_out[3 * H2 + j] = h;   // h2 at flat offset 1536
    }
}

extern "C" void kernel_launch(void* const* d_in, const int* in_sizes, int n_in,
                              void* d_out, int out_size, void* d_ws, size_t ws_size,
                              hipStream_t stream) {
    const int*   ids   = (const int*)d_in[0];
    const float* h1_in = (const float*)d_in[1];
    const float* h2_in = (const float*)d_in[2];
    const float* emb   = (const float*)d_in[3];
    const float* w_ih1 = (const float*)d_in[4];
    const float* w_hh1 = (const float*)d_in[5];
    const float* b_ih1 = (const float*)d_in[6];
    const float* b_hh1 = (const float*)d_in[7];
    const float* w_ih2 = (const float*)d_in[8];
    const float* w_hh2 = (const float*)d_in[9];
    const float* b_ih2 = (const float*)d_in[10];
    const float* b_hh2 = (const float*)d_in[11];
    float* out = (float*)d_out;
    float* gh2 = (float*)d_ws;   // 1536 floats

    gru_k1<<<H1 + 3 * H2, 256, 0, stream>>>(ids, h1_in, h2_in, emb,
                                            w_ih1, w_hh1, b_ih1, b_hh1,
                                            w_hh2, b_hh2, out, gh2);
    gru_k2<<<H2, 256, 0, stream>>>(h2_in, w_ih2, b_ih2, gh2, out);
}